// Round 1
// baseline (517.040 us; speedup 1.0000x reference)
//
#include <hip/hip_runtime.h>
#include <stdint.h>

typedef _Float16 f16;
typedef _Float16 f16x4 __attribute__((ext_vector_type(4)));
typedef _Float16 f16x8 __attribute__((ext_vector_type(8)));
typedef float floatx4 __attribute__((ext_vector_type(4)));

#define B_ROWS 4096
#define D_IN   768
#define H_DIM  16384
#define TOPK_N 32
#define NC     40   // candidate count for exact refinement

typedef __attribute__((address_space(1))) const unsigned int g_uint;
typedef __attribute__((address_space(3))) unsigned int l_uint;

__device__ __forceinline__ void gload_lds16(const void* g, void* l) {
    __builtin_amdgcn_global_load_lds((g_uint*)(uintptr_t)g,
                                     (l_uint*)(uint32_t)(uintptr_t)l,
                                     16, 0, 0);
}

// ---------------- split x -> f16 ----------------
__global__ __launch_bounds__(256) void split_x(const float* __restrict__ x,
                                               f16* __restrict__ xhi) {
    const int i = blockIdx.x * 256 + threadIdx.x;
    const float4 q = ((const float4*)x)[i];
    f16x4 h;
    h[0] = (f16)q.x; h[1] = (f16)q.y; h[2] = (f16)q.z; h[3] = (f16)q.w;
    ((f16x4*)xhi)[i] = h;
}

// ---------------- transpose + hi/lo split of W_enc ----------------
// W [768][16384] f32  ->  whiT/wloT [16384][768] f16 (k contiguous)
__global__ __launch_bounds__(256) void split_transpose_w(const float* __restrict__ W,
                                                         f16* __restrict__ whiT,
                                                         f16* __restrict__ wloT) {
    __shared__ float tile[64][65];
    const int kb = blockIdx.x;      // 0..11
    const int nb = blockIdx.y;      // 0..255
    const int t  = threadIdx.x;
    const int col = t & 63;
    const int r4  = t >> 6;
#pragma unroll
    for (int p = 0; p < 16; ++p) {
        const int kr = p * 4 + r4;
        tile[kr][col] = W[(size_t)(kb * 64 + kr) * H_DIM + nb * 64 + col];
    }
    __syncthreads();
    const int n  = t >> 2;
    const int kq = (t & 3) * 16;
    f16x8 h0, h1, l0, l1;
#pragma unroll
    for (int j = 0; j < 8; ++j) {
        const float v0 = tile[kq + j][n];
        const f16 ha = (f16)v0; h0[j] = ha; l0[j] = (f16)(v0 - (float)ha);
        const float v1 = tile[kq + 8 + j][n];
        const f16 hb = (f16)v1; h1[j] = hb; l1[j] = (f16)(v1 - (float)hb);
    }
    const size_t base = (size_t)(nb * 64 + n) * D_IN + kb * 64 + kq;
    *(f16x8*)&whiT[base]     = h0;
    *(f16x8*)&whiT[base + 8] = h1;
    *(f16x8*)&wloT[base]     = l0;
    *(f16x8*)&wloT[base + 8] = l1;
}

// ---------------- encode GEMM: preact = x @ W_enc + b_enc (f16 MFMA) ----------------
// 128x128 tile, BK=32, 4 waves, global_load_lds(16B) staging, XOR k-chunk swizzle.
__global__ __launch_bounds__(256, 2) void encode_gemm(const f16* __restrict__ xhi,
                                                      const f16* __restrict__ whiT,
                                                      const float* __restrict__ b_enc,
                                                      float* __restrict__ preact) {
    __shared__ f16 lsA[128][32];
    __shared__ f16 lsB[128][32];
    const int tid  = threadIdx.x;
    const int bid  = blockIdx.x;
    const int m0   = (bid >> 7) << 7;
    const int n0   = (bid & 127) << 7;
    const int lane = tid & 63;
    const int wave = tid >> 6;
    const int m_off = (wave & 1) << 6;
    const int n_off = (wave >> 1) << 6;
    const int fr = lane & 15;   // A-row / B-col within 16
    const int fk = lane >> 4;   // k-chunk 0..3

    floatx4 acc[4][4];
    const floatx4 zero = {0.f, 0.f, 0.f, 0.f};
#pragma unroll
    for (int i = 0; i < 4; ++i)
#pragma unroll
        for (int j = 0; j < 4; ++j) acc[i][j] = zero;

    // staging assignment: chunk c = r*4+q (16B each); thread covers rows sr and sr+64
    const int sq  = tid & 3;
    const int sr  = tid >> 2;
    const int kq8 = (sq ^ (sr & 3)) << 3;   // swizzled source k-offset (halves)
    const f16* gA0 = xhi  + (size_t)(m0 + sr) * D_IN + kq8;
    const f16* gA1 = gA0 + (size_t)64 * D_IN;
    const f16* gB0 = whiT + (size_t)(n0 + sr) * D_IN + kq8;
    const f16* gB1 = gB0 + (size_t)64 * D_IN;
    f16* lA0 = &lsA[sr][sq * 8];
    f16* lA1 = &lsA[sr + 64][sq * 8];
    f16* lB0 = &lsB[sr][sq * 8];
    f16* lB1 = &lsB[sr + 64][sq * 8];

    for (int kt = 0; kt < D_IN / 32; ++kt) {
        const int ko = kt * 32;
        gload_lds16(gA0 + ko, lA0);
        gload_lds16(gA1 + ko, lA1);
        gload_lds16(gB0 + ko, lB0);
        gload_lds16(gB1 + ko, lB1);
        __syncthreads();
        f16x8 af[4], bf[4];
#pragma unroll
        for (int mi = 0; mi < 4; ++mi) {
            const int r = m_off + mi * 16 + fr;
            af[mi] = *(const f16x8*)&lsA[r][(fk ^ (r & 3)) * 8];
        }
#pragma unroll
        for (int ni = 0; ni < 4; ++ni) {
            const int r = n_off + ni * 16 + fr;
            bf[ni] = *(const f16x8*)&lsB[r][(fk ^ (r & 3)) * 8];
        }
#pragma unroll
        for (int mi = 0; mi < 4; ++mi)
#pragma unroll
            for (int ni = 0; ni < 4; ++ni)
                acc[mi][ni] = __builtin_amdgcn_mfma_f32_16x16x32_f16(
                    af[mi], bf[ni], acc[mi][ni], 0, 0, 0);
        __syncthreads();
    }

    // epilogue: C/D layout col=lane&15 (n), row=(lane>>4)*4+j (m); add bias, store fp32
#pragma unroll
    for (int ni = 0; ni < 4; ++ni) {
        const int n = n0 + n_off + ni * 16 + fr;
        const float bias = b_enc[n];
#pragma unroll
        for (int mi = 0; mi < 4; ++mi) {
            const int m = m0 + m_off + mi * 16 + fk * 4;
            float* p = preact + (size_t)m * H_DIM + n;
#pragma unroll
            for (int j = 0; j < 4; ++j)
                p[(size_t)j * H_DIM] = acc[mi][ni][j] + bias;
        }
    }
}

// ---------------- approx top-NC candidate selection (radix select on relu'd bits) ----------------
__global__ __launch_bounds__(256) void topk_approx(const float* __restrict__ preact,
                                                   int* __restrict__ cand) {
    const int row = blockIdx.x;
    const int t   = threadIdx.x;
    const float* pr = preact + (size_t)row * H_DIM;
    float vr[64];
#pragma unroll
    for (int i = 0; i < 16; ++i) {
        const float4 q = ((const float4*)pr)[t + 256 * i];
        vr[4 * i + 0] = q.x; vr[4 * i + 1] = q.y;
        vr[4 * i + 2] = q.z; vr[4 * i + 3] = q.w;
    }
    __shared__ unsigned hist[256];
    __shared__ unsigned sbin, sneed;
    __shared__ unsigned tie_idx[64];
    __shared__ unsigned tie_cnt, out_cnt;

    unsigned prefix = 0u, need = NC;
#pragma unroll
    for (int lvl = 0; lvl < 4; ++lvl) {
        const int shift = 24 - 8 * lvl;
        hist[t] = 0u;
        __syncthreads();
#pragma unroll
        for (int e = 0; e < 64; ++e) {
            unsigned k = __float_as_uint(vr[e]);
            k = (vr[e] > 0.f) ? k : 0u;
            if ((((unsigned long long)(k ^ prefix)) >> (shift + 8)) == 0ull)
                atomicAdd(&hist[(k >> shift) & 255u], 1u);
        }
        __syncthreads();
        // suffix (reverse inclusive) scan over 256 bins
        unsigned sval = hist[t];
        for (int off = 1; off < 256; off <<= 1) {
            const unsigned add = (t + off < 256) ? hist[t + off] : 0u;
            __syncthreads();
            sval += add;
            hist[t] = sval;
            __syncthreads();
        }
        const unsigned above = (t < 255) ? hist[t + 1] : 0u;
        if (sval >= need && above < need) { sbin = (unsigned)t; sneed = need - above; }
        __syncthreads();
        prefix |= (sbin << shift);
        need = sneed;
        __syncthreads();
    }

    const unsigned theta = prefix;
    if (t == 0) { tie_cnt = 0u; out_cnt = 0u; }
    __syncthreads();
    int* crow = cand + row * NC;
#pragma unroll
    for (int e = 0; e < 64; ++e) {
        unsigned k = __float_as_uint(vr[e]);
        k = (vr[e] > 0.f) ? k : 0u;
        const int gidx = 4 * t + 1024 * (e >> 2) + (e & 3);
        if (k > theta) {
            const unsigned p = atomicAdd(&out_cnt, 1u);
            crow[p] = gidx;
        } else if (theta != 0u && k == theta) {
            const unsigned p = atomicAdd(&tie_cnt, 1u);
            if (p < 64u) tie_idx[p] = (unsigned)gidx;
        }
    }
    __syncthreads();
    if (t == 0) {
        unsigned p   = out_cnt;                    // == NC - need
        unsigned cnt = tie_cnt < 64u ? tie_cnt : 64u;
        unsigned take = need < cnt ? need : cnt;
        for (unsigned a = 0; a < take; ++a) {      // smallest tie indices first
            unsigned best = a;
            for (unsigned b = a + 1; b < cnt; ++b)
                if (tie_idx[b] < tie_idx[best]) best = b;
            const unsigned tmp = tie_idx[a]; tie_idx[a] = tie_idx[best]; tie_idx[best] = tmp;
            crow[p++] = (int)tie_idx[a];
        }
        while (p < NC) crow[p++] = -1;
    }
}

// ---------------- exact fp32 refinement of candidates + hidden write ----------------
__global__ __launch_bounds__(256) void refine_kernel(const float* __restrict__ x,
                                                     const f16* __restrict__ whiT,
                                                     const f16* __restrict__ wloT,
                                                     const float* __restrict__ b_enc,
                                                     const int* __restrict__ cand,
                                                     float* __restrict__ hidden,
                                                     float* __restrict__ topv,
                                                     int* __restrict__ topi) {
    const int row  = blockIdx.x;
    const int t    = threadIdx.x;
    const int lane = t & 63;
    const int wave = t >> 6;
    __shared__ float xr[D_IN];
    __shared__ float cv[NC];
    __shared__ int   ci[NC];
    __shared__ float selv[TOPK_N];
    __shared__ int   seli[TOPK_N];

    if (t < NC) ci[t] = cand[row * NC + t];
#pragma unroll
    for (int j = 0; j < 3; ++j)
        xr[t + 256 * j] = x[(size_t)row * D_IN + t + 256 * j];
    __syncthreads();

    for (int c = wave; c < NC; c += 4) {
        const int n = ci[c];
        float sum = 0.f;
        if (n >= 0) {
            const f16* wh = whiT + (size_t)n * D_IN;
            const f16* wl = wloT + (size_t)n * D_IN;
#pragma unroll
            for (int j = 0; j < 12; ++j) {
                const int k = lane + 64 * j;
                sum += xr[k] * ((float)wh[k] + (float)wl[k]);
            }
        }
#pragma unroll
        for (int off = 32; off > 0; off >>= 1) sum += __shfl_down(sum, off);
        if (lane == 0) cv[c] = (n >= 0) ? (sum + b_enc[n]) : -3.0e38f;
    }
    __syncthreads();

    if (t < NC) {
        const float vi = cv[t];
        const int   ii = ci[t];
        int rank = 0;
        for (int j = 0; j < NC; ++j) {
            const float vj = cv[j];
            const int   ij = ci[j];
            rank += (vj > vi) || (vj == vi && (ij < ii || (ij == ii && j < t)));
        }
        if (rank < TOPK_N) { selv[rank] = vi; seli[rank] = ii; }
    }
    __syncthreads();

    float* hrow = hidden + (size_t)row * H_DIM;
#pragma unroll
    for (int i = 0; i < 64; ++i) hrow[t + 256 * i] = 0.f;
    __syncthreads();
    if (t < TOPK_N) {
        const int n = seli[t];
        float v = selv[t];
        v = (n >= 0) ? fmaxf(v, 0.f) : 0.f;
        topv[row * TOPK_N + t] = v;
        topi[row * TOPK_N + t] = (n >= 0) ? n : 0;
        if (v > 0.f) hrow[n] = v;
    }
}

// ---------------- sparse decode: out = relu(hidden_sparse @ W_dec + b_dec) ----------------
__global__ __launch_bounds__(256) void decode_kernel(const float* __restrict__ topv,
                                                     const int* __restrict__ topi,
                                                     const float* __restrict__ Wdec,
                                                     const float* __restrict__ bdec,
                                                     float* __restrict__ out) {
    const int row = blockIdx.x;
    const int t   = threadIdx.x;
    __shared__ float sv[TOPK_N];
    __shared__ int   si[TOPK_N];
    if (t < TOPK_N) { sv[t] = topv[row * TOPK_N + t]; si[t] = topi[row * TOPK_N + t]; }
    __syncthreads();
    float a0 = 0.f, a1 = 0.f, a2 = 0.f;
#pragma unroll 4
    for (int j = 0; j < TOPK_N; ++j) {
        const float v = sv[j];
        const float* wr = Wdec + (size_t)si[j] * D_IN;
        a0 += v * wr[t];
        a1 += v * wr[t + 256];
        a2 += v * wr[t + 512];
    }
    float* orow = out + (size_t)row * D_IN;
    orow[t]       = fmaxf(a0 + bdec[t], 0.f);
    orow[t + 256] = fmaxf(a1 + bdec[t + 256], 0.f);
    orow[t + 512] = fmaxf(a2 + bdec[t + 512], 0.f);
}

extern "C" void kernel_launch(void* const* d_in, const int* in_sizes, int n_in,
                              void* d_out, int out_size, void* d_ws, size_t ws_size,
                              hipStream_t stream) {
    const float* x     = (const float*)d_in[0];
    const float* W_enc = (const float*)d_in[1];
    const float* b_enc = (const float*)d_in[2];
    const float* W_dec = (const float*)d_in[3];
    const float* b_dec = (const float*)d_in[4];

    float* out    = (float*)d_out;
    float* hidden = out + (size_t)B_ROWS * D_IN;
    float* preact = hidden + (size_t)B_ROWS * H_DIM;

    uint8_t* ws = (uint8_t*)d_ws;
    size_t off = 0;
    f16* xhi  = (f16*)(ws + off); off += (size_t)B_ROWS * D_IN * 2;
    f16* whiT = (f16*)(ws + off); off += (size_t)H_DIM * D_IN * 2;
    f16* wloT = (f16*)(ws + off); off += (size_t)H_DIM * D_IN * 2;
    int*   cand = (int*)(ws + off);  off += (size_t)B_ROWS * NC * 4;
    float* topv = (float*)(ws + off); off += (size_t)B_ROWS * TOPK_N * 4;
    int*   topi = (int*)(ws + off);  off += (size_t)B_ROWS * TOPK_N * 4;
    if (off > ws_size) return;  // insufficient workspace -> fail visibly

    split_x<<<(B_ROWS * D_IN / 4) / 256, 256, 0, stream>>>(x, xhi);
    dim3 gw(D_IN / 64, H_DIM / 64);
    split_transpose_w<<<gw, 256, 0, stream>>>(W_enc, whiT, wloT);
    encode_gemm<<<(B_ROWS / 128) * (H_DIM / 128), 256, 0, stream>>>(xhi, whiT, b_enc, preact);
    topk_approx<<<B_ROWS, 256, 0, stream>>>(preact, cand);
    refine_kernel<<<B_ROWS, 256, 0, stream>>>(x, whiT, wloT, b_enc, cand, hidden, topv, topi);
    decode_kernel<<<B_ROWS, 256, 0, stream>>>(topv, topi, W_dec, b_dec, out);
}

// Round 2
// 422.881 us; speedup vs baseline: 1.2227x; 1.2227x over previous
//
#include <hip/hip_runtime.h>
#include <stdint.h>

typedef _Float16 f16;
typedef _Float16 f16x4 __attribute__((ext_vector_type(4)));
typedef _Float16 f16x8 __attribute__((ext_vector_type(8)));
typedef float floatx4 __attribute__((ext_vector_type(4)));

#define B_ROWS 4096
#define D_IN   768
#define H_DIM  16384
#define TOPK_N 32
#define NC     40    // target candidate count (superset of exact top-32)
#define NCAP   192   // hard cap on candidates per row

typedef __attribute__((address_space(1))) const unsigned int g_uint;
typedef __attribute__((address_space(3))) unsigned int l_uint;

__device__ __forceinline__ void gload_lds16(const void* g, void* l) {
    __builtin_amdgcn_global_load_lds((g_uint*)(uintptr_t)g,
                                     (l_uint*)(uint32_t)(uintptr_t)l,
                                     16, 0, 0);
}

// ---------------- split x -> f16 ----------------
__global__ __launch_bounds__(256) void split_x(const float* __restrict__ x,
                                               f16* __restrict__ xhi) {
    const int i = blockIdx.x * 256 + threadIdx.x;
    const float4 q = ((const float4*)x)[i];
    f16x4 h;
    h[0] = (f16)q.x; h[1] = (f16)q.y; h[2] = (f16)q.z; h[3] = (f16)q.w;
    ((f16x4*)xhi)[i] = h;
}

// ---------------- transpose + hi/lo split of W_enc ----------------
// W [768][16384] f32  ->  whiT/wloT [16384][768] f16 (k contiguous)
__global__ __launch_bounds__(256) void split_transpose_w(const float* __restrict__ W,
                                                         f16* __restrict__ whiT,
                                                         f16* __restrict__ wloT) {
    __shared__ float tile[64][65];
    const int kb = blockIdx.x;      // 0..11
    const int nb = blockIdx.y;      // 0..255
    const int t  = threadIdx.x;
    const int col = t & 63;
    const int r4  = t >> 6;
#pragma unroll
    for (int p = 0; p < 16; ++p) {
        const int kr = p * 4 + r4;
        tile[kr][col] = W[(size_t)(kb * 64 + kr) * H_DIM + nb * 64 + col];
    }
    __syncthreads();
    const int n  = t >> 2;
    const int kq = (t & 3) * 16;
    f16x8 h0, h1, l0, l1;
#pragma unroll
    for (int j = 0; j < 8; ++j) {
        const float v0 = tile[kq + j][n];
        const f16 ha = (f16)v0; h0[j] = ha; l0[j] = (f16)(v0 - (float)ha);
        const float v1 = tile[kq + 8 + j][n];
        const f16 hb = (f16)v1; h1[j] = hb; l1[j] = (f16)(v1 - (float)hb);
    }
    const size_t base = (size_t)(nb * 64 + n) * D_IN + kb * 64 + kq;
    *(f16x8*)&whiT[base]     = h0;
    *(f16x8*)&whiT[base + 8] = h1;
    *(f16x8*)&wloT[base]     = l0;
    *(f16x8*)&wloT[base + 8] = l1;
}

// ---------------- encode GEMM: preact = x @ W_enc + b_enc (f16 MFMA) ----------------
__global__ __launch_bounds__(256, 2) void encode_gemm(const f16* __restrict__ xhi,
                                                      const f16* __restrict__ whiT,
                                                      const float* __restrict__ b_enc,
                                                      float* __restrict__ preact) {
    __shared__ f16 lsA[128][32];
    __shared__ f16 lsB[128][32];
    const int tid  = threadIdx.x;
    const int bid  = blockIdx.x;
    const int m0   = (bid >> 7) << 7;
    const int n0   = (bid & 127) << 7;
    const int lane = tid & 63;
    const int wave = tid >> 6;
    const int m_off = (wave & 1) << 6;
    const int n_off = (wave >> 1) << 6;
    const int fr = lane & 15;   // A-row / B-col within 16
    const int fk = lane >> 4;   // k-chunk 0..3

    floatx4 acc[4][4];
    const floatx4 zero = {0.f, 0.f, 0.f, 0.f};
#pragma unroll
    for (int i = 0; i < 4; ++i)
#pragma unroll
        for (int j = 0; j < 4; ++j) acc[i][j] = zero;

    const int sq  = tid & 3;
    const int sr  = tid >> 2;
    const int kq8 = (sq ^ (sr & 3)) << 3;   // swizzled source k-offset (halves)
    const f16* gA0 = xhi  + (size_t)(m0 + sr) * D_IN + kq8;
    const f16* gA1 = gA0 + (size_t)64 * D_IN;
    const f16* gB0 = whiT + (size_t)(n0 + sr) * D_IN + kq8;
    const f16* gB1 = gB0 + (size_t)64 * D_IN;
    f16* lA0 = &lsA[sr][sq * 8];
    f16* lA1 = &lsA[sr + 64][sq * 8];
    f16* lB0 = &lsB[sr][sq * 8];
    f16* lB1 = &lsB[sr + 64][sq * 8];

    for (int kt = 0; kt < D_IN / 32; ++kt) {
        const int ko = kt * 32;
        gload_lds16(gA0 + ko, lA0);
        gload_lds16(gA1 + ko, lA1);
        gload_lds16(gB0 + ko, lB0);
        gload_lds16(gB1 + ko, lB1);
        __syncthreads();
        f16x8 af[4], bf[4];
#pragma unroll
        for (int mi = 0; mi < 4; ++mi) {
            const int r = m_off + mi * 16 + fr;
            af[mi] = *(const f16x8*)&lsA[r][(fk ^ (r & 3)) * 8];
        }
#pragma unroll
        for (int ni = 0; ni < 4; ++ni) {
            const int r = n_off + ni * 16 + fr;
            bf[ni] = *(const f16x8*)&lsB[r][(fk ^ (r & 3)) * 8];
        }
#pragma unroll
        for (int mi = 0; mi < 4; ++mi)
#pragma unroll
            for (int ni = 0; ni < 4; ++ni)
                acc[mi][ni] = __builtin_amdgcn_mfma_f32_16x16x32_f16(
                    af[mi], bf[ni], acc[mi][ni], 0, 0, 0);
        __syncthreads();
    }

#pragma unroll
    for (int ni = 0; ni < 4; ++ni) {
        const int n = n0 + n_off + ni * 16 + fr;
        const float bias = b_enc[n];
#pragma unroll
        for (int mi = 0; mi < 4; ++mi) {
            const int m = m0 + m_off + mi * 16 + fk * 4;
            float* p = preact + (size_t)m * H_DIM + n;
#pragma unroll
            for (int j = 0; j < 4; ++j)
                p[(size_t)j * H_DIM] = acc[mi][ni][j] + bias;
        }
    }
}

// ---------------- candidate selection: single-level linear-bin select ----------------
// Non-positive preacts are exactly droppable: a selected value <=0 relu's to 0
// and scatters 0 into hidden == unselected. So only positives are binned.
__global__ __launch_bounds__(256) void topk_approx(const float* __restrict__ preact,
                                                   int* __restrict__ cand,
                                                   int* __restrict__ ccnt) {
    const int row = blockIdx.x;
    const int t   = threadIdx.x;
    const float* pr = preact + (size_t)row * H_DIM;
    float vr[64];
    float m = 0.f;
#pragma unroll
    for (int i = 0; i < 16; ++i) {
        const float4 q = ((const float4*)pr)[t + 256 * i];
        vr[4 * i + 0] = q.x; vr[4 * i + 1] = q.y;
        vr[4 * i + 2] = q.z; vr[4 * i + 3] = q.w;
        m = fmaxf(m, fmaxf(fmaxf(q.x, q.y), fmaxf(q.z, q.w)));
    }
#pragma unroll
    for (int off = 32; off > 0; off >>= 1) m = fmaxf(m, __shfl_down(m, off));

    __shared__ float wmax[4];
    __shared__ unsigned hist[256];
    __shared__ unsigned sbin_s, out_cnt;
    if ((t & 63) == 0) wmax[t >> 6] = m;
    hist[t] = 0u;
    if (t == 0) { sbin_s = 0u; out_cnt = 0u; }
    __syncthreads();
    const float M = fmaxf(fmaxf(wmax[0], wmax[1]), fmaxf(wmax[2], wmax[3]));
    int* crow = cand + row * NCAP;

    if (M > 0.f) {
        const float scale = 256.0f / M;
#pragma unroll
        for (int e = 0; e < 64; ++e) {
            const float v = vr[e];
            if (v > 0.f) {
                int b = (int)(v * scale); b = b > 255 ? 255 : b;
                atomicAdd(&hist[b], 1u);
            }
        }
        __syncthreads();
        // suffix (reverse inclusive) scan over 256 bins
        unsigned sval = hist[t];
        for (int off = 1; off < 256; off <<= 1) {
            const unsigned add = (t + off < 256) ? hist[t + off] : 0u;
            __syncthreads();
            sval += add;
            hist[t] = sval;
            __syncthreads();
        }
        const unsigned above = (t < 255) ? hist[t + 1] : 0u;
        if (sval >= NC && above < NC) sbin_s = (unsigned)t;
        __syncthreads();
        const int sbin = (int)sbin_s;   // 0 if total positives < NC -> collect all
#pragma unroll
        for (int e = 0; e < 64; ++e) {
            const float v = vr[e];
            if (v > 0.f) {
                int b = (int)(v * scale); b = b > 255 ? 255 : b;
                if (b >= sbin) {
                    const unsigned p = atomicAdd(&out_cnt, 1u);
                    if (p < NCAP) crow[p] = 4 * t + 1024 * (e >> 2) + (e & 3);
                }
            }
        }
        __syncthreads();
    }
    if (t == 0) ccnt[row] = (int)(out_cnt < NCAP ? out_cnt : NCAP);
}

// ---------------- exact fp32 refinement of candidates + hidden write ----------------
__global__ __launch_bounds__(256) void refine_kernel(const float* __restrict__ x,
                                                     const f16* __restrict__ whiT,
                                                     const f16* __restrict__ wloT,
                                                     const float* __restrict__ b_enc,
                                                     const int* __restrict__ cand,
                                                     const int* __restrict__ ccnt,
                                                     float* __restrict__ hidden,
                                                     float* __restrict__ topv,
                                                     int* __restrict__ topi) {
    const int row  = blockIdx.x;
    const int t    = threadIdx.x;
    const int lane = t & 63;
    const int wave = t >> 6;
    __shared__ float xr[D_IN];
    __shared__ float cv[NCAP];
    __shared__ int   ci[NCAP];
    __shared__ float selv[TOPK_N];
    __shared__ int   seli[TOPK_N];

    const int cnt = ccnt[row];
    if (t < NCAP) ci[t] = (t < cnt) ? cand[row * NCAP + t] : -1;
    if (t < TOPK_N) { selv[t] = -3.0e38f; seli[t] = -1; }
#pragma unroll
    for (int j = 0; j < 3; ++j)
        xr[t + 256 * j] = x[(size_t)row * D_IN + t + 256 * j];
    __syncthreads();

    for (int c = wave; c < cnt; c += 4) {
        const int n = ci[c];
        float sum = 0.f;
        const f16* wh = whiT + (size_t)n * D_IN;
        const f16* wl = wloT + (size_t)n * D_IN;
#pragma unroll
        for (int j = 0; j < 12; ++j) {
            const int k = lane + 64 * j;
            sum += xr[k] * ((float)wh[k] + (float)wl[k]);
        }
#pragma unroll
        for (int off = 32; off > 0; off >>= 1) sum += __shfl_down(sum, off);
        if (lane == 0) cv[c] = sum + b_enc[n];
    }
    __syncthreads();

    if (t < cnt) {
        const float vi = cv[t];
        const int   ii = ci[t];
        int rank = 0;
        for (int j = 0; j < cnt; ++j) {
            const float vj = cv[j];
            rank += (vj > vi) || (vj == vi && ci[j] < ii);
        }
        if (rank < TOPK_N) { selv[rank] = vi; seli[rank] = ii; }
    }
    __syncthreads();

    float* hrow = hidden + (size_t)row * H_DIM;
    const float4 z = {0.f, 0.f, 0.f, 0.f};
#pragma unroll
    for (int i = 0; i < 16; ++i) ((float4*)hrow)[t + 256 * i] = z;
    __syncthreads();
    if (t < TOPK_N) {
        const int n = seli[t];
        float v = selv[t];
        v = (n >= 0) ? fmaxf(v, 0.f) : 0.f;
        topv[row * TOPK_N + t] = v;
        topi[row * TOPK_N + t] = (n >= 0) ? n : 0;
        if (v > 0.f) hrow[n] = v;
    }
}

// ---------------- sparse decode: out = relu(hidden_sparse @ W_dec + b_dec) ----------------
__global__ __launch_bounds__(256) void decode_kernel(const float* __restrict__ topv,
                                                     const int* __restrict__ topi,
                                                     const float* __restrict__ Wdec,
                                                     const float* __restrict__ bdec,
                                                     float* __restrict__ out) {
    const int row = blockIdx.x;
    const int t   = threadIdx.x;
    __shared__ float sv[TOPK_N];
    __shared__ int   si[TOPK_N];
    if (t < TOPK_N) { sv[t] = topv[row * TOPK_N + t]; si[t] = topi[row * TOPK_N + t]; }
    __syncthreads();
    float a0 = 0.f, a1 = 0.f, a2 = 0.f;
#pragma unroll 4
    for (int j = 0; j < TOPK_N; ++j) {
        const float v = sv[j];
        const float* wr = Wdec + (size_t)si[j] * D_IN;
        a0 += v * wr[t];
        a1 += v * wr[t + 256];
        a2 += v * wr[t + 512];
    }
    float* orow = out + (size_t)row * D_IN;
    orow[t]       = fmaxf(a0 + bdec[t], 0.f);
    orow[t + 256] = fmaxf(a1 + bdec[t + 256], 0.f);
    orow[t + 512] = fmaxf(a2 + bdec[t + 512], 0.f);
}

extern "C" void kernel_launch(void* const* d_in, const int* in_sizes, int n_in,
                              void* d_out, int out_size, void* d_ws, size_t ws_size,
                              hipStream_t stream) {
    const float* x     = (const float*)d_in[0];
    const float* W_enc = (const float*)d_in[1];
    const float* b_enc = (const float*)d_in[2];
    const float* W_dec = (const float*)d_in[3];
    const float* b_dec = (const float*)d_in[4];

    float* out    = (float*)d_out;
    float* hidden = out + (size_t)B_ROWS * D_IN;
    float* preact = hidden + (size_t)B_ROWS * H_DIM;

    uint8_t* ws = (uint8_t*)d_ws;
    size_t off = 0;
    f16* xhi  = (f16*)(ws + off); off += (size_t)B_ROWS * D_IN * 2;
    f16* whiT = (f16*)(ws + off); off += (size_t)H_DIM * D_IN * 2;
    f16* wloT = (f16*)(ws + off); off += (size_t)H_DIM * D_IN * 2;
    int*   cand = (int*)(ws + off);  off += (size_t)B_ROWS * NCAP * 4;
    int*   ccnt = (int*)(ws + off);  off += (size_t)B_ROWS * 4;
    float* topv = (float*)(ws + off); off += (size_t)B_ROWS * TOPK_N * 4;
    int*   topi = (int*)(ws + off);  off += (size_t)B_ROWS * TOPK_N * 4;
    if (off > ws_size) return;  // insufficient workspace -> fail visibly

    split_x<<<(B_ROWS * D_IN / 4) / 256, 256, 0, stream>>>(x, xhi);
    dim3 gw(D_IN / 64, H_DIM / 64);
    split_transpose_w<<<gw, 256, 0, stream>>>(W_enc, whiT, wloT);
    encode_gemm<<<(B_ROWS / 128) * (H_DIM / 128), 256, 0, stream>>>(xhi, whiT, b_enc, preact);
    topk_approx<<<B_ROWS, 256, 0, stream>>>(preact, cand, ccnt);
    refine_kernel<<<B_ROWS, 256, 0, stream>>>(x, whiT, wloT, b_enc, cand, ccnt, hidden, topv, topi);
    decode_kernel<<<B_ROWS, 256, 0, stream>>>(topv, topi, W_dec, b_dec, out);
}

// Round 5
// 390.755 us; speedup vs baseline: 1.3232x; 1.0822x over previous
//
#include <hip/hip_runtime.h>
#include <stdint.h>

typedef _Float16 f16;
typedef _Float16 f16x4 __attribute__((ext_vector_type(4)));
typedef _Float16 f16x8 __attribute__((ext_vector_type(8)));
typedef float floatx4 __attribute__((ext_vector_type(4)));

#define B_ROWS 4096
#define D_IN   768
#define H_DIM  16384
#define TOPK_N 32
#define NC     40    // target candidate count (superset of exact top-32)
#define NCAP   192   // hard cap on candidates per row

#define BM 256
#define BN 256
#define BK 64
#define NKT (D_IN / BK)   // 12 K-tiles

typedef __attribute__((address_space(1))) const unsigned int g_uint;
typedef __attribute__((address_space(3))) unsigned int l_uint;

__device__ __forceinline__ void gload_lds16(const void* g, void* l) {
    __builtin_amdgcn_global_load_lds((g_uint*)(uintptr_t)g,
                                     (l_uint*)(uint32_t)(uintptr_t)l,
                                     16, 0, 0);
}

// ---------------- split x -> f16 ----------------
__global__ __launch_bounds__(256) void split_x(const float* __restrict__ x,
                                               f16* __restrict__ xhi) {
    const int i = blockIdx.x * 256 + threadIdx.x;
    const float4 q = ((const float4*)x)[i];
    f16x4 h;
    h[0] = (f16)q.x; h[1] = (f16)q.y; h[2] = (f16)q.z; h[3] = (f16)q.w;
    ((f16x4*)xhi)[i] = h;
}

// ---------------- transpose + hi/lo split of W_enc ----------------
// W [768][16384] f32  ->  whiT/wloT [16384][768] f16 (k contiguous)
__global__ __launch_bounds__(256) void split_transpose_w(const float* __restrict__ W,
                                                         f16* __restrict__ whiT,
                                                         f16* __restrict__ wloT) {
    __shared__ float tile[64][65];
    const int kb = blockIdx.x;      // 0..11
    const int nb = blockIdx.y;      // 0..255
    const int t  = threadIdx.x;
    const int col = t & 63;
    const int r4  = t >> 6;
#pragma unroll
    for (int p = 0; p < 16; ++p) {
        const int kr = p * 4 + r4;
        tile[kr][col] = W[(size_t)(kb * 64 + kr) * H_DIM + nb * 64 + col];
    }
    __syncthreads();
    const int n  = t >> 2;
    const int kq = (t & 3) * 16;
    f16x8 h0, h1, l0, l1;
#pragma unroll
    for (int j = 0; j < 8; ++j) {
        const float v0 = tile[kq + j][n];
        const f16 ha = (f16)v0; h0[j] = ha; l0[j] = (f16)(v0 - (float)ha);
        const float v1 = tile[kq + 8 + j][n];
        const f16 hb = (f16)v1; h1[j] = hb; l1[j] = (f16)(v1 - (float)hb);
    }
    const size_t base = (size_t)(nb * 64 + n) * D_IN + kb * 64 + kq;
    *(f16x8*)&whiT[base]     = h0;
    *(f16x8*)&whiT[base + 8] = h1;
    *(f16x8*)&wloT[base]     = l0;
    *(f16x8*)&wloT[base + 8] = l1;
}

// ---------------- encode GEMM: 256x256, BK=64, classic dbuf (1 __syncthreads/tile) ----
// LDS per buffer: A[256][64] f16 (32 KiB) + B[256][64] f16 (32 KiB); 2 buffers = 128 KiB.
// k-slot swizzle: logical 16B-slot s of row r lives at physical slot s ^ (r & 7).
// Applied on BOTH sides (rule #21): pre-swizzled global source + swizzled ds_read;
// LDS destination stays linear for global_load_lds.
// No hand-counted vmcnt anywhere: __syncthreads() (full vmcnt0+lgkm0 drain) gives
// RAW (tile t landed) and WAR (prev reads drained) regardless of compiler-emitted VMEM.
#define STAGE(buf, kt) do {                                                        \
    const int ko_ = (kt) * BK;                                                     \
    _Pragma("unroll")                                                              \
    for (int q_ = 0; q_ < 4; ++q_)                                                 \
        gload_lds16(xhi + aoff[q_] + ko_, sA + (buf) * 16384 + q_ * 4096 + tid * 8);\
    _Pragma("unroll")                                                              \
    for (int q_ = 0; q_ < 4; ++q_)                                                 \
        gload_lds16(whiT + boff[q_] + ko_, sB + (buf) * 16384 + q_ * 4096 + tid * 8);\
} while (0)

__global__ __launch_bounds__(512, 2) void encode_gemm256(const f16* __restrict__ xhi,
                                                         const f16* __restrict__ whiT,
                                                         const float* __restrict__ b_enc,
                                                         float* __restrict__ preact) {
    extern __shared__ __align__(16) f16 smem[];
    f16* sA = smem;            // 2 * 256 * 64 f16
    f16* sB = smem + 32768;    // 2 * 256 * 64 f16
    const int tid = threadIdx.x;
    const int bid = blockIdx.x;
    const int swz = (bid & 7) * 128 + (bid >> 3);   // XCD swizzle, nwg=1024 % 8 == 0
    const int m0 = (swz >> 6) * BM;                 // 16 m-blocks
    const int n0 = (swz & 63) * BN;                 // 64 n-blocks
    const int lane = tid & 63;
    const int wr = (tid >> 6) >> 2;                 // 0..1
    const int wc = (tid >> 6) & 3;                  // 0..3
    const int fr = lane & 15;
    const int fk = lane >> 4;
    // reader slot offsets (f16 units) for ks=0/1: slot (fk+4*ks) ^ (fr&7)
    const int sxk0 = ((fk)     ^ (fr & 7)) * 8;
    const int sxk1 = ((fk + 4) ^ (fr & 7)) * 8;

    // staging source offsets (f16 units): thread covers rows q*64 + (tid>>3),
    // 16B chunk c = tid&7, source k-slot pre-swizzled by (row&7) = ((tid>>3)&7)
    const int sw = ((tid & 7) ^ ((tid >> 3) & 7)) << 3;
    int aoff[4], boff[4];
#pragma unroll
    for (int q = 0; q < 4; ++q) {
        const int p = q * 64 + (tid >> 3);
        aoff[q] = (m0 + p) * D_IN + sw;
        boff[q] = (n0 + p) * D_IN + sw;
    }

    floatx4 acc[8][4];
    const floatx4 zero = {0.f, 0.f, 0.f, 0.f};
#pragma unroll
    for (int i = 0; i < 8; ++i)
#pragma unroll
        for (int j = 0; j < 4; ++j) acc[i][j] = zero;

    STAGE(0, 0);
    for (int t = 0; t < NKT; ++t) {
        __syncthreads();                 // drains vmcnt(0)+lgkmcnt(0): tile t landed,
                                         // and iter t-1's ds_reads are complete in all waves
        if (t + 1 < NKT) STAGE((t + 1) & 1, t + 1);
        const int bufo = (t & 1) * 16384;
#pragma unroll
        for (int ks = 0; ks < 2; ++ks) {
            const int sx = ks ? sxk1 : sxk0;
            f16x8 af[8], bf[4];
#pragma unroll
            for (int mi = 0; mi < 8; ++mi)
                af[mi] = *(const f16x8*)(sA + bufo + (wr * 128 + mi * 16 + fr) * 64 + sx);
#pragma unroll
            for (int ni = 0; ni < 4; ++ni)
                bf[ni] = *(const f16x8*)(sB + bufo + (wc * 64 + ni * 16 + fr) * 64 + sx);
#pragma unroll
            for (int mi = 0; mi < 8; ++mi)
#pragma unroll
                for (int ni = 0; ni < 4; ++ni)
                    acc[mi][ni] = __builtin_amdgcn_mfma_f32_16x16x32_f16(
                        af[mi], bf[ni], acc[mi][ni], 0, 0, 0);
        }
    }

    // epilogue: C/D col = lane&15, row = (lane>>4)*4 + j; add bias, fp32 store
#pragma unroll
    for (int ni = 0; ni < 4; ++ni) {
        const int col = n0 + wc * 64 + ni * 16 + fr;
        const float bias = b_enc[col];
#pragma unroll
        for (int mi = 0; mi < 8; ++mi) {
            const int row = m0 + wr * 128 + mi * 16 + fk * 4;
            float* p = preact + (size_t)row * H_DIM + col;
#pragma unroll
            for (int j = 0; j < 4; ++j)
                p[(size_t)j * H_DIM] = acc[mi][ni][j] + bias;
        }
    }
}

// ---------------- candidate selection: single-level linear-bin select ----------------
__global__ __launch_bounds__(256) void topk_approx(const float* __restrict__ preact,
                                                   int* __restrict__ cand,
                                                   int* __restrict__ ccnt) {
    const int row = blockIdx.x;
    const int t   = threadIdx.x;
    const float* pr = preact + (size_t)row * H_DIM;
    float vr[64];
    float m = 0.f;
#pragma unroll
    for (int i = 0; i < 16; ++i) {
        const float4 q = ((const float4*)pr)[t + 256 * i];
        vr[4 * i + 0] = q.x; vr[4 * i + 1] = q.y;
        vr[4 * i + 2] = q.z; vr[4 * i + 3] = q.w;
        m = fmaxf(m, fmaxf(fmaxf(q.x, q.y), fmaxf(q.z, q.w)));
    }
#pragma unroll
    for (int off = 32; off > 0; off >>= 1) m = fmaxf(m, __shfl_down(m, off));

    __shared__ float wmax[4];
    __shared__ unsigned hist[256];
    __shared__ unsigned sbin_s, out_cnt;
    if ((t & 63) == 0) wmax[t >> 6] = m;
    hist[t] = 0u;
    if (t == 0) { sbin_s = 0u; out_cnt = 0u; }
    __syncthreads();
    const float M = fmaxf(fmaxf(wmax[0], wmax[1]), fmaxf(wmax[2], wmax[3]));
    int* crow = cand + row * NCAP;

    if (M > 0.f) {
        const float scale = 256.0f / M;
#pragma unroll
        for (int e = 0; e < 64; ++e) {
            const float v = vr[e];
            if (v > 0.f) {
                int b = (int)(v * scale); b = b > 255 ? 255 : b;
                atomicAdd(&hist[b], 1u);
            }
        }
        __syncthreads();
        unsigned sval = hist[t];
        for (int off = 1; off < 256; off <<= 1) {
            const unsigned add = (t + off < 256) ? hist[t + off] : 0u;
            __syncthreads();
            sval += add;
            hist[t] = sval;
            __syncthreads();
        }
        const unsigned above = (t < 255) ? hist[t + 1] : 0u;
        if (sval >= NC && above < NC) sbin_s = (unsigned)t;
        __syncthreads();
        const int sbin = (int)sbin_s;
#pragma unroll
        for (int e = 0; e < 64; ++e) {
            const float v = vr[e];
            if (v > 0.f) {
                int b = (int)(v * scale); b = b > 255 ? 255 : b;
                if (b >= sbin) {
                    const unsigned p = atomicAdd(&out_cnt, 1u);
                    if (p < NCAP) crow[p] = 4 * t + 1024 * (e >> 2) + (e & 3);
                }
            }
        }
        __syncthreads();
    }
    if (t == 0) ccnt[row] = (int)(out_cnt < NCAP ? out_cnt : NCAP);
}

// ---------------- exact fp32 refinement of candidates + hidden write ----------------
__global__ __launch_bounds__(256) void refine_kernel(const float* __restrict__ x,
                                                     const f16* __restrict__ whiT,
                                                     const f16* __restrict__ wloT,
                                                     const float* __restrict__ b_enc,
                                                     const int* __restrict__ cand,
                                                     const int* __restrict__ ccnt,
                                                     float* __restrict__ hidden,
                                                     float* __restrict__ topv,
                                                     int* __restrict__ topi) {
    const int row  = blockIdx.x;
    const int t    = threadIdx.x;
    const int lane = t & 63;
    const int wave = t >> 6;
    __shared__ float xr[D_IN];
    __shared__ float cv[NCAP];
    __shared__ int   ci[NCAP];
    __shared__ float selv[TOPK_N];
    __shared__ int   seli[TOPK_N];

    const int cnt = ccnt[row];
    if (t < NCAP) ci[t] = (t < cnt) ? cand[row * NCAP + t] : -1;
    if (t < TOPK_N) { selv[t] = -3.0e38f; seli[t] = -1; }
#pragma unroll
    for (int j = 0; j < 3; ++j)
        xr[t + 256 * j] = x[(size_t)row * D_IN + t + 256 * j];
    __syncthreads();

    for (int c = wave; c < cnt; c += 4) {
        const int n = ci[c];
        float sum = 0.f;
        const f16* wh = whiT + (size_t)n * D_IN;
        const f16* wl = wloT + (size_t)n * D_IN;
#pragma unroll
        for (int j = 0; j < 12; ++j) {
            const int k = lane + 64 * j;
            sum += xr[k] * ((float)wh[k] + (float)wl[k]);
        }
#pragma unroll
        for (int off = 32; off > 0; off >>= 1) sum += __shfl_down(sum, off);
        if (lane == 0) cv[c] = sum + b_enc[n];
    }
    __syncthreads();

    if (t < cnt) {
        const float vi = cv[t];
        const int   ii = ci[t];
        int rank = 0;
        for (int j = 0; j < cnt; ++j) {
            const float vj = cv[j];
            rank += (vj > vi) || (vj == vi && ci[j] < ii);
        }
        if (rank < TOPK_N) { selv[rank] = vi; seli[rank] = ii; }
    }
    __syncthreads();

    float* hrow = hidden + (size_t)row * H_DIM;
    const float4 z = {0.f, 0.f, 0.f, 0.f};
#pragma unroll
    for (int i = 0; i < 16; ++i) ((float4*)hrow)[t + 256 * i] = z;
    __syncthreads();
    if (t < TOPK_N) {
        const int n = seli[t];
        float v = selv[t];
        v = (n >= 0) ? fmaxf(v, 0.f) : 0.f;
        topv[row * TOPK_N + t] = v;
        topi[row * TOPK_N + t] = (n >= 0) ? n : 0;
        if (v > 0.f) hrow[n] = v;
    }
}

// ---------------- sparse decode: out = relu(hidden_sparse @ W_dec + b_dec) ----------------
__global__ __launch_bounds__(256) void decode_kernel(const float* __restrict__ topv,
                                                     const int* __restrict__ topi,
                                                     const float* __restrict__ Wdec,
                                                     const float* __restrict__ bdec,
                                                     float* __restrict__ out) {
    const int row = blockIdx.x;
    const int t   = threadIdx.x;
    __shared__ float sv[TOPK_N];
    __shared__ int   si[TOPK_N];
    if (t < TOPK_N) { sv[t] = topv[row * TOPK_N + t]; si[t] = topi[row * TOPK_N + t]; }
    __syncthreads();
    float a0 = 0.f, a1 = 0.f, a2 = 0.f;
#pragma unroll 4
    for (int j = 0; j < TOPK_N; ++j) {
        const float v = sv[j];
        const float* wr = Wdec + (size_t)si[j] * D_IN;
        a0 += v * wr[t];
        a1 += v * wr[t + 256];
        a2 += v * wr[t + 512];
    }
    float* orow = out + (size_t)row * D_IN;
    orow[t]       = fmaxf(a0 + bdec[t], 0.f);
    orow[t + 256] = fmaxf(a1 + bdec[t + 256], 0.f);
    orow[t + 512] = fmaxf(a2 + bdec[t + 512], 0.f);
}

extern "C" void kernel_launch(void* const* d_in, const int* in_sizes, int n_in,
                              void* d_out, int out_size, void* d_ws, size_t ws_size,
                              hipStream_t stream) {
    const float* x     = (const float*)d_in[0];
    const float* W_enc = (const float*)d_in[1];
    const float* b_enc = (const float*)d_in[2];
    const float* W_dec = (const float*)d_in[3];
    const float* b_dec = (const float*)d_in[4];

    float* out    = (float*)d_out;
    float* hidden = out + (size_t)B_ROWS * D_IN;
    float* preact = hidden + (size_t)B_ROWS * H_DIM;

    uint8_t* ws = (uint8_t*)d_ws;
    size_t off = 0;
    f16* xhi  = (f16*)(ws + off); off += (size_t)B_ROWS * D_IN * 2;
    f16* whiT = (f16*)(ws + off); off += (size_t)H_DIM * D_IN * 2;
    f16* wloT = (f16*)(ws + off); off += (size_t)H_DIM * D_IN * 2;
    int*   cand = (int*)(ws + off);  off += (size_t)B_ROWS * NCAP * 4;
    int*   ccnt = (int*)(ws + off);  off += (size_t)B_ROWS * 4;
    float* topv = (float*)(ws + off); off += (size_t)B_ROWS * TOPK_N * 4;
    int*   topi = (int*)(ws + off);  off += (size_t)B_ROWS * TOPK_N * 4;
    if (off > ws_size) return;  // insufficient workspace -> fail visibly

    hipFuncSetAttribute(reinterpret_cast<const void*>(encode_gemm256),
                        hipFuncAttributeMaxDynamicSharedMemorySize, 131072);

    split_x<<<(B_ROWS * D_IN / 4) / 256, 256, 0, stream>>>(x, xhi);
    dim3 gw(D_IN / 64, H_DIM / 64);
    split_transpose_w<<<gw, 256, 0, stream>>>(W_enc, whiT, wloT);
    encode_gemm256<<<(B_ROWS / BM) * (H_DIM / BN), 512, 131072, stream>>>(xhi, whiT, b_enc, preact);
    topk_approx<<<B_ROWS, 256, 0, stream>>>(preact, cand, ccnt);
    refine_kernel<<<B_ROWS, 256, 0, stream>>>(x, whiT, wloT, b_enc, cand, ccnt, hidden, topv, topi);
    decode_kernel<<<B_ROWS, 256, 0, stream>>>(topv, topi, W_dec, b_dec, out);
}